// Round 1
// baseline (133.732 us; speedup 1.0000x reference)
//
#include <hip/hip_runtime.h>

#define Hh 384
#define Ww 384
#define Bb 4
#define NN 64
#define HW (Hh*Ww)

// ---------------- Ainv = (I + 0.1*A)^-1 via banded LU (pentadiagonal) -------
__global__ void k_ainv(float* __restrict__ Ainv) {
    __shared__ float sd[NN], su1[NN], su2[NN], sb1[NN], sL1[NN], sL2[NN], sdinv[NN];
    int t = threadIdx.x;
    if (t == 0) {
        for (int i = 0; i < NN; ++i) { sd[i] = 0.f; su1[i] = 0.f; su2[i] = 0.f; }
        // A = 0.01*(D1^T D1) + 0.01*(D2^T D2), bands only
        for (int k = 0; k < NN-1; ++k) { sd[k] += 0.01f; sd[k+1] += 0.01f; su1[k] -= 0.01f; }
        for (int k = 0; k < NN-2; ++k) {
            sd[k] += 0.01f; sd[k+1] += 0.04f; sd[k+2] += 0.01f;
            su1[k] -= 0.02f; su1[k+1] -= 0.02f; su2[k] += 0.01f;
        }
        for (int i = 0; i < NN; ++i) {
            sd[i]  = 1.0f + 0.1f*sd[i];
            su1[i] = 0.1f*su1[i];
            su2[i] = 0.1f*su2[i];
            sb1[i] = su1[i];            // lower band m[i+1][i] (symmetric init)
        }
        // banded LU, no pivoting (diagonally dominant, cond ~1.02)
        for (int i = 0; i < NN; ++i) {
            float di = sd[i];
            if (i+1 < NN) {
                float l = sb1[i]/di; sL1[i] = l;
                sd[i+1] -= l*su1[i];
                if (i+2 < NN) su1[i+1] -= l*su2[i];
            }
            if (i+2 < NN) {
                float l = su2[i]/di; sL2[i] = l;   // m[i+2][i] never modified earlier
                sb1[i+1] -= l*su1[i];
                sd[i+2]  -= l*su2[i];
            }
        }
    }
    __syncthreads();
    sdinv[t] = 1.0f/sd[t];
    __syncthreads();
    // each thread solves M x = e_t  (forward L, backward U); x = column t of Ainv
    float y[NN];
#pragma unroll
    for (int i = 0; i < NN; ++i) {
        float v = (i == t) ? 1.0f : 0.0f;
        if (i >= 1) v -= sL1[i-1]*y[i-1];
        if (i >= 2) v -= sL2[i-2]*y[i-2];
        y[i] = v;
    }
    float x[NN];
#pragma unroll
    for (int ii = 0; ii < NN; ++ii) {
        int i = NN-1-ii;
        float v = y[i];
        if (i+1 < NN) v -= su1[i]*x[i+1];
        if (i+2 < NN) v -= su2[i]*x[i+2];
        x[i] = v*sdinv[i];
    }
    for (int i = 0; i < NN; ++i) Ainv[i*NN + t] = x[i];  // symmetric; [i][t] ok
}

// ---------------- separable DoG conv -> gimg [B][2][H][W], x EXTGRADFAC ----
#define TILE 32
#define HALO 8
__global__ void k_conv(const float* __restrict__ img, float* __restrict__ gimg) {
    __shared__ float sIn[TILE+2*HALO][TILE+2*HALO];      // 48x48
    __shared__ float sColG[TILE+2*HALO][TILE];           // 48x32
    __shared__ float sColD[TILE+2*HALO][TILE];
    __shared__ float gtap[17], dtap[17];
    const int b  = blockIdx.z;
    const int x0 = blockIdx.x * TILE;
    const int y0 = blockIdx.y * TILE;
    const int tid = threadIdx.x;
    if (tid == 0) {
        float s = 0.f;
        for (int i = 0; i < 17; ++i) {
            float xv = (float)(i - 8);
            float e  = expf(-0.5f * (xv*0.5f)*(xv*0.5f));
            gtap[i] = e; s += e;
            dtap[i] = -(xv*0.25f) * e;
        }
        for (int i = 0; i < 17; ++i) gtap[i] /= s;
    }
    const float* im = img + b*HW;
    for (int idx = tid; idx < 48*48; idx += blockDim.x) {
        int r = idx / 48, c = idx % 48;
        int gx = x0 + r - HALO, gy = y0 + c - HALO;
        float v = 0.f;
        if (gx >= 0 && gx < Hh && gy >= 0 && gy < Ww) v = im[gx*Ww + gy];
        sIn[r][c] = v;
    }
    __syncthreads();
    for (int idx = tid; idx < 48*TILE; idx += blockDim.x) {
        int r = idx / TILE, c = idx % TILE;
        float ag = 0.f, ad = 0.f;
#pragma unroll
        for (int k = 0; k < 17; ++k) {
            float v = sIn[r][c+k];
            ag += gtap[k]*v;
            ad += dtap[k]*v;
        }
        sColG[r][c] = ag; sColD[r][c] = ad;
    }
    __syncthreads();
    float* g0 = gimg + (size_t)(b*2+0)*HW;
    float* g1 = gimg + (size_t)(b*2+1)*HW;
    for (int idx = tid; idx < TILE*TILE; idx += blockDim.x) {
        int xo = idx / TILE, c = idx % TILE;
        float a0 = 0.f, a1 = 0.f;
#pragma unroll
        for (int k = 0; k < 17; ++k) {
            a0 += dtap[k]*sColG[xo+k][c];
            a1 += gtap[k]*sColD[xo+k][c];
        }
        int gx = x0+xo, gy = y0+c;
        g0[gx*Ww+gy] = 10.f*a0;
        g1[gx*Ww+gy] = 10.f*a1;
    }
}

// ---------------- snake evolution: 20 implicit-Euler steps -----------------
__global__ void k_snake(const float* __restrict__ gimg, const float* __restrict__ init,
                        const float* __restrict__ Ainv, float* __restrict__ pos) {
    __shared__ float2 txy[NN];
    const int b = blockIdx.x, i = threadIdx.x;
    // own row of Ainv in registers
    float ar[NN];
#pragma unroll
    for (int j = 0; j < NN; ++j) ar[j] = Ainv[i*NN + j];
    float px = init[(b*NN + i)*2 + 0];
    float py = init[(b*NN + i)*2 + 1];
    const float* g0 = gimg + (size_t)(b*2)*HW;
    const float* g1 = g0 + HW;
    for (int s = 0; s < 20; ++s) {
        float x = fminf(fmaxf(px, 0.f), (float)(Hh-1));
        float y = fminf(fmaxf(py, 0.f), (float)(Ww-1));
        int x0i = (int)floorf(x); x0i = min(max(x0i, 0), Hh-2);
        int y0i = (int)floorf(y); y0i = min(max(y0i, 0), Ww-2);
        float fx = x - (float)x0i, fy = y - (float)y0i;
        int base = x0i*Ww + y0i;
        float v00 = g0[base],    v01 = g0[base+1];
        float v10 = g0[base+Ww], v11 = g0[base+Ww+1];
        float top = v00*(1.f-fy) + v01*fy;
        float bot = v10*(1.f-fy) + v11*fy;
        float f0  = top*(1.f-fx) + bot*fx;
        v00 = g1[base];    v01 = g1[base+1];
        v10 = g1[base+Ww]; v11 = g1[base+Ww+1];
        top = v00*(1.f-fy) + v01*fy;
        bot = v10*(1.f-fy) + v11*fy;
        float f1 = top*(1.f-fx) + bot*fx;
        txy[i] = make_float2(px + 0.1f*f0, py + 0.1f*f1);
        __syncthreads();
        float ax = 0.f, ay = 0.f;
#pragma unroll
        for (int j = 0; j < NN; ++j) {
            float2 tv = txy[j];
            ax = fmaf(ar[j], tv.x, ax);
            ay = fmaf(ar[j], tv.y, ay);
        }
        px = ax; py = ay;
        __syncthreads();
    }
    pos[(b*NN+i)*2+0] = px;
    pos[(b*NN+i)*2+1] = py;
}

// ---------------- radial widths: 1 wave per (b,node), early exit -----------
__global__ void k_widths(const float* __restrict__ pred, const float* __restrict__ pos,
                         float* __restrict__ widths) {
    const int blk = blockIdx.x;
    const int b = blk / NN, node = blk % NN;
    const int lane = threadIdx.x;
    const float sx = rintf(pos[(b*NN+node)*2+0]);   // round-half-even, matches jnp.round
    const float sy = rintf(pos[(b*NN+node)*2+1]);
    const float* p = pred + (size_t)b*HW;
    const bool active = lane < 36;
    const float theta = (float)(10*lane) * 0.017453292519943295f;
    const float c = cosf(theta), s = sinf(theta);
    float w = 0.f;
    for (int r = 1; r < Hh; ++r) {
        float rf = (float)r;
        bool hit = false, oob = false;
        if (active) {
            int xi = (int)floorf(sx + rf*c);
            int yi = (int)floorf(sy + rf*s);
            bool inb = (xi >= 0) & (xi < Hh) & (yi >= 0) & (yi < Ww);
            if (!inb) oob = true;
            else if (p[xi*Ww + yi] > 0.f) hit = true;  // sigmoid(-p)<0.5 <=> p>0
        }
        unsigned long long mh = __ballot(hit);
        unsigned long long mo = __ballot(oob);
        if (mh | mo) { w = mh ? (rf - 1.f) : 0.f; break; }
    }
    if (lane == 0) widths[b*NN + node] = w;
}

// ---------------- render dmap/pmap + fused loss partial sums ---------------
__global__ void k_render(const float* __restrict__ pred, const float* __restrict__ pos,
                         const float* __restrict__ widths, float* __restrict__ partial) {
    __shared__ float nx[NN], ny[NN], nw[NN];
    __shared__ float red[256];
    const int b = blockIdx.y;
    const int tid = threadIdx.x;
    if (tid < NN) {
        nx[tid] = pos[(b*NN+tid)*2+0];
        ny[tid] = pos[(b*NN+tid)*2+1];
        nw[tid] = widths[b*NN+tid];
    }
    __syncthreads();
    const int pix = blockIdx.x*256 + tid;
    const float fx = (float)(pix / Ww), fy = (float)(pix % Ww);
    float m1 = 1e30f, m2 = 1e30f;
    for (int s2 = 0; s2 < NN-1; ++s2) {
        float p0x = nx[s2], p0y = ny[s2];
        float vx = nx[s2+1]-p0x, vy = ny[s2+1]-p0y;
        float vv = vx*vx + vy*vy + 1e-8f;
        float dx = fx - p0x, dy = fy - p0y;
        float t = (dx*vx + dy*vy) / vv;
        t = fminf(fmaxf(t, 0.f), 1.f);
        float ex = dx - t*vx, ey = dy - t*vy;
        float dist = sqrtf(ex*ex + ey*ey + 1e-12f);
        float wt = nw[s2] + t*(nw[s2+1]-nw[s2]);
        m1 = fminf(m1, dist);
        m2 = fminf(m2, dist - wt);
    }
    float dmap = fminf(m1, 15.f);
    float pm = (m2 <= 0.f) ? 1.f : 0.f;
    float pv = pred[(size_t)b*HW + pix];
    float sg = 1.f/(1.f + expf(-pv));
    float t1 = pv - dmap, t2 = sg - pm;
    float acc = t1*t1 + t2*t2;
    red[tid] = acc; __syncthreads();
    for (int off = 128; off > 0; off >>= 1) {
        if (tid < off) red[tid] += red[tid+off];
        __syncthreads();
    }
    if (tid == 0) partial[b*gridDim.x + blockIdx.x] = red[0];
}

__global__ void k_final(const float* __restrict__ partial, float* __restrict__ out, int n) {
    __shared__ double red[256];
    const int tid = threadIdx.x;
    double a = 0.0;
    for (int i = tid; i < n; i += 256) a += (double)partial[i];
    red[tid] = a; __syncthreads();
    for (int off = 128; off > 0; off >>= 1) {
        if (tid < off) red[tid] += red[tid+off];
        __syncthreads();
    }
    if (tid == 0) out[0] = (float)(red[0] / (double)((size_t)Bb*HW));
}

extern "C" void kernel_launch(void* const* d_in, const int* in_sizes, int n_in,
                              void* d_out, int out_size, void* d_ws, size_t ws_size,
                              hipStream_t stream) {
    const float* pred = (const float*)d_in[0];   // [4,1,384,384] f32
    const float* init = (const float*)d_in[1];   // [4,64,2] f32
    float* out = (float*)d_out;                  // scalar loss
    char* ws = (char*)d_ws;
    // ws layout (bytes): Ainv 16384 | pos 2048 | widths 1024 | partial 9216 | gimg 4718592
    float* Ainv    = (float*)(ws);
    float* pos     = (float*)(ws + 16384);
    float* widths  = (float*)(ws + 18432);
    float* partial = (float*)(ws + 19456);
    float* gimg    = (float*)(ws + 28672);

    k_ainv  <<<dim3(1),        dim3(64),  0, stream>>>(Ainv);
    k_conv  <<<dim3(12,12,4),  dim3(256), 0, stream>>>(pred, gimg);
    k_snake <<<dim3(4),        dim3(64),  0, stream>>>(gimg, init, Ainv, pos);
    k_widths<<<dim3(Bb*NN),    dim3(64),  0, stream>>>(pred, pos, widths);
    k_render<<<dim3(576,Bb),   dim3(256), 0, stream>>>(pred, pos, widths, partial);
    k_final <<<dim3(1),        dim3(256), 0, stream>>>(partial, out, Bb*576);
}

// Round 2
// 96.504 us; speedup vs baseline: 1.3858x; 1.3858x over previous
//
#include <hip/hip_runtime.h>

#define Hh 384
#define Ww 384
#define Bb 4
#define NN 64
#define HW (Hh*Ww)

// ---------------- separable DoG conv -> gimg interleaved [B][H][W][2] ------
#define TILE 32
#define HALO 8
__global__ void k_conv(const float* __restrict__ img, float2* __restrict__ gimg) {
    __shared__ float sIn[TILE+2*HALO][TILE+2*HALO];      // 48x48
    __shared__ float sColG[TILE+2*HALO][TILE];           // 48x32
    __shared__ float sColD[TILE+2*HALO][TILE];
    __shared__ float gtap[17], dtap[17];
    const int b  = blockIdx.z;
    const int x0 = blockIdx.x * TILE;
    const int y0 = blockIdx.y * TILE;
    const int tid = threadIdx.x;
    if (tid == 0) {
        float s = 0.f;
        for (int i = 0; i < 17; ++i) {
            float xv = (float)(i - 8);
            float e  = expf(-0.5f * (xv*0.5f)*(xv*0.5f));
            gtap[i] = e; s += e;
            dtap[i] = -(xv*0.25f) * e;
        }
        for (int i = 0; i < 17; ++i) gtap[i] /= s;
    }
    const float* im = img + b*HW;
    for (int idx = tid; idx < 48*48; idx += blockDim.x) {
        int r = idx / 48, c = idx % 48;
        int gx = x0 + r - HALO, gy = y0 + c - HALO;
        float v = 0.f;
        if (gx >= 0 && gx < Hh && gy >= 0 && gy < Ww) v = im[gx*Ww + gy];
        sIn[r][c] = v;
    }
    __syncthreads();
    for (int idx = tid; idx < 48*TILE; idx += blockDim.x) {
        int r = idx / TILE, c = idx % TILE;
        float ag = 0.f, ad = 0.f;
#pragma unroll
        for (int k = 0; k < 17; ++k) {
            float v = sIn[r][c+k];
            ag += gtap[k]*v;
            ad += dtap[k]*v;
        }
        sColG[r][c] = ag; sColD[r][c] = ad;
    }
    __syncthreads();
    float2* gg = gimg + (size_t)b*HW;
    for (int idx = tid; idx < TILE*TILE; idx += blockDim.x) {
        int xo = idx / TILE, c = idx % TILE;
        float a0 = 0.f, a1 = 0.f;
#pragma unroll
        for (int k = 0; k < 17; ++k) {
            a0 += dtap[k]*sColG[xo+k][c];
            a1 += gtap[k]*sColD[xo+k][c];
        }
        int gx = x0+xo, gy = y0+c;
        gg[gx*Ww+gy] = make_float2(10.f*a0, 10.f*a1);
    }
}

// ---------------- snake: fused Ainv build + 20 implicit-Euler steps --------
// 256 threads: node i = tid>>2, quarter q = tid&3. Each thread holds 16
// Ainv coefficients in registers (no spill); matvec partials combined via
// __shfl_xor (lanes i*4+q are contiguous within a wave).
__global__ __launch_bounds__(256) void k_snake(const float2* __restrict__ gimg,
                        const float* __restrict__ init, float* __restrict__ pos) {
    __shared__ float sA[NN][NN+1];
    __shared__ float sd[NN], su1[NN], su2[NN], sb1[NN], sL1[NN], sL2[NN], sdinv[NN];
    __shared__ float2 stxy[NN];
    const int b = blockIdx.x;
    const int tid = threadIdx.x;
    const int i = tid >> 2;
    const int q = tid & 3;

    // ---- build (I + 0.1*A)^-1 into sA (banded LU, same math as before) ----
    if (tid == 0) {
        for (int k = 0; k < NN; ++k) { sd[k] = 0.f; su1[k] = 0.f; su2[k] = 0.f; }
        for (int k = 0; k < NN-1; ++k) { sd[k] += 0.01f; sd[k+1] += 0.01f; su1[k] -= 0.01f; }
        for (int k = 0; k < NN-2; ++k) {
            sd[k] += 0.01f; sd[k+1] += 0.04f; sd[k+2] += 0.01f;
            su1[k] -= 0.02f; su1[k+1] -= 0.02f; su2[k] += 0.01f;
        }
        for (int k = 0; k < NN; ++k) {
            sd[k]  = 1.0f + 0.1f*sd[k];
            su1[k] = 0.1f*su1[k];
            su2[k] = 0.1f*su2[k];
            sb1[k] = su1[k];
        }
        for (int k = 0; k < NN; ++k) {
            float di = sd[k];
            if (k+1 < NN) {
                float l = sb1[k]/di; sL1[k] = l;
                sd[k+1] -= l*su1[k];
                if (k+2 < NN) su1[k+1] -= l*su2[k];
            }
            if (k+2 < NN) {
                float l = su2[k]/di; sL2[k] = l;
                sb1[k+1] -= l*su1[k];
                sd[k+2]  -= l*su2[k];
            }
        }
    }
    __syncthreads();
    if (tid < NN) sdinv[tid] = 1.0f/sd[tid];
    __syncthreads();
    if (tid < NN) {
        const int t = tid;
        float y[NN], x[NN];
#pragma unroll
        for (int k = 0; k < NN; ++k) {
            float v = (k == t) ? 1.0f : 0.0f;
            if (k >= 1) v -= sL1[k-1]*y[k-1];
            if (k >= 2) v -= sL2[k-2]*y[k-2];
            y[k] = v;
        }
#pragma unroll
        for (int kk = 0; kk < NN; ++kk) {
            int k = NN-1-kk;
            float v = y[k];
            if (k+1 < NN) v -= su1[k]*x[k+1];
            if (k+2 < NN) v -= su2[k]*x[k+2];
            x[k] = v*sdinv[k];
        }
        for (int k = 0; k < NN; ++k) sA[k][t] = x[k];   // column t (symmetric)
    }
    __syncthreads();

    // ---- 16 coefficients per thread: Ainv[i][q*16 .. q*16+15] ----
    float ar[16];
#pragma unroll
    for (int k = 0; k < 16; ++k) ar[k] = sA[i][q*16 + k];

    float px = init[(b*NN + i)*2 + 0];
    float py = init[(b*NN + i)*2 + 1];
    const float2* g = gimg + (size_t)b*HW;

    for (int s = 0; s < 20; ++s) {
        float x = fminf(fmaxf(px, 0.f), (float)(Hh-1));
        float y = fminf(fmaxf(py, 0.f), (float)(Ww-1));
        int x0i = (int)floorf(x); x0i = min(max(x0i, 0), Hh-2);
        int y0i = (int)floorf(y); y0i = min(max(y0i, 0), Ww-2);
        float fx = x - (float)x0i, fy = y - (float)y0i;
        int base = x0i*Ww + y0i;
        float2 v00 = g[base],    v01 = g[base+1];
        float2 v10 = g[base+Ww], v11 = g[base+Ww+1];
        float t0x = v00.x*(1.f-fy) + v01.x*fy;
        float t0y = v00.y*(1.f-fy) + v01.y*fy;
        float b0x = v10.x*(1.f-fy) + v11.x*fy;
        float b0y = v10.y*(1.f-fy) + v11.y*fy;
        float f0 = t0x*(1.f-fx) + b0x*fx;
        float f1 = t0y*(1.f-fx) + b0y*fx;
        if (q == 0) stxy[i] = make_float2(px + 0.1f*f0, py + 0.1f*f1);
        __syncthreads();
        float ax = 0.f, ay = 0.f;
#pragma unroll
        for (int k = 0; k < 16; ++k) {
            float2 tv = stxy[q*16 + k];
            ax = fmaf(ar[k], tv.x, ax);
            ay = fmaf(ar[k], tv.y, ay);
        }
        ax += __shfl_xor(ax, 1); ay += __shfl_xor(ay, 1);
        ax += __shfl_xor(ax, 2); ay += __shfl_xor(ay, 2);
        px = ax; py = ay;
        __syncthreads();
    }
    if (q == 0) {
        pos[(b*NN+i)*2+0] = px;
        pos[(b*NN+i)*2+1] = py;
    }
}

// ---------------- radial widths: 1 wave per (b,node), early exit -----------
__global__ void k_widths(const float* __restrict__ pred, const float* __restrict__ pos,
                         float* __restrict__ widths) {
    const int blk = blockIdx.x;
    const int b = blk / NN, node = blk % NN;
    const int lane = threadIdx.x;
    const float sx = rintf(pos[(b*NN+node)*2+0]);   // round-half-even, matches jnp.round
    const float sy = rintf(pos[(b*NN+node)*2+1]);
    const float* p = pred + (size_t)b*HW;
    const bool active = lane < 36;
    const float theta = (float)(10*lane) * 0.017453292519943295f;
    const float c = cosf(theta), s = sinf(theta);
    float w = 0.f;
    for (int r = 1; r < Hh; ++r) {
        float rf = (float)r;
        bool hit = false, oob = false;
        if (active) {
            int xi = (int)floorf(sx + rf*c);
            int yi = (int)floorf(sy + rf*s);
            bool inb = (xi >= 0) & (xi < Hh) & (yi >= 0) & (yi < Ww);
            if (!inb) oob = true;
            else if (p[xi*Ww + yi] > 0.f) hit = true;  // sigmoid(-p)<0.5 <=> p>0
        }
        unsigned long long mh = __ballot(hit);
        unsigned long long mo = __ballot(oob);
        if (mh | mo) { w = mh ? (rf - 1.f) : 0.f; break; }
    }
    if (lane == 0) widths[b*NN + node] = w;
}

// ---------------- render dmap/pmap + fused loss partial sums ---------------
__global__ void k_render(const float* __restrict__ pred, const float* __restrict__ pos,
                         const float* __restrict__ widths, float* __restrict__ partial) {
    __shared__ float nx[NN], ny[NN], nw[NN];
    __shared__ float red[256];
    const int b = blockIdx.y;
    const int tid = threadIdx.x;
    if (tid < NN) {
        nx[tid] = pos[(b*NN+tid)*2+0];
        ny[tid] = pos[(b*NN+tid)*2+1];
        nw[tid] = widths[b*NN+tid];
    }
    __syncthreads();
    const int pix = blockIdx.x*256 + tid;
    const float fx = (float)(pix / Ww), fy = (float)(pix % Ww);
    float m1 = 1e30f, m2 = 1e30f;
    for (int s2 = 0; s2 < NN-1; ++s2) {
        float p0x = nx[s2], p0y = ny[s2];
        float vx = nx[s2+1]-p0x, vy = ny[s2+1]-p0y;
        float vv = vx*vx + vy*vy + 1e-8f;
        float dx = fx - p0x, dy = fy - p0y;
        float t = (dx*vx + dy*vy) / vv;
        t = fminf(fmaxf(t, 0.f), 1.f);
        float ex = dx - t*vx, ey = dy - t*vy;
        float dist = sqrtf(ex*ex + ey*ey + 1e-12f);
        float wt = nw[s2] + t*(nw[s2+1]-nw[s2]);
        m1 = fminf(m1, dist);
        m2 = fminf(m2, dist - wt);
    }
    float dmap = fminf(m1, 15.f);
    float pm = (m2 <= 0.f) ? 1.f : 0.f;
    float pv = pred[(size_t)b*HW + pix];
    float sg = 1.f/(1.f + expf(-pv));
    float t1 = pv - dmap, t2 = sg - pm;
    float acc = t1*t1 + t2*t2;
    red[tid] = acc; __syncthreads();
    for (int off = 128; off > 0; off >>= 1) {
        if (tid < off) red[tid] += red[tid+off];
        __syncthreads();
    }
    if (tid == 0) partial[b*gridDim.x + blockIdx.x] = red[0];
}

__global__ void k_final(const float* __restrict__ partial, float* __restrict__ out, int n) {
    __shared__ double red[256];
    const int tid = threadIdx.x;
    double a = 0.0;
    for (int i = tid; i < n; i += 256) a += (double)partial[i];
    red[tid] = a; __syncthreads();
    for (int off = 128; off > 0; off >>= 1) {
        if (tid < off) red[tid] += red[tid+off];
        __syncthreads();
    }
    if (tid == 0) out[0] = (float)(red[0] / (double)((size_t)Bb*HW));
}

extern "C" void kernel_launch(void* const* d_in, const int* in_sizes, int n_in,
                              void* d_out, int out_size, void* d_ws, size_t ws_size,
                              hipStream_t stream) {
    const float* pred = (const float*)d_in[0];   // [4,1,384,384] f32
    const float* init = (const float*)d_in[1];   // [4,64,2] f32
    float* out = (float*)d_out;                  // scalar loss
    char* ws = (char*)d_ws;
    // ws layout (bytes): (reserved 16384) | pos 2048 | widths 1024 | partial 9216 | gimg 4718592 (float2)
    float* pos     = (float*)(ws + 16384);
    float* widths  = (float*)(ws + 18432);
    float* partial = (float*)(ws + 19456);
    float2* gimg   = (float2*)(ws + 28672);

    k_conv  <<<dim3(12,12,4),  dim3(256), 0, stream>>>(pred, gimg);
    k_snake <<<dim3(4),        dim3(256), 0, stream>>>(gimg, init, pos);
    k_widths<<<dim3(Bb*NN),    dim3(64),  0, stream>>>(pred, pos, widths);
    k_render<<<dim3(576,Bb),   dim3(256), 0, stream>>>(pred, pos, widths, partial);
    k_final <<<dim3(1),        dim3(256), 0, stream>>>(partial, out, Bb*576);
}

// Round 3
// 67.959 us; speedup vs baseline: 1.9678x; 1.4200x over previous
//
#include <hip/hip_runtime.h>

#define Hh 384
#define Ww 384
#define Bb 4
#define NN 64
#define HW (Hh*Ww)

// ---------------- separable DoG conv -> gimg interleaved [B][H][W][2] ------
#define TILE 32
#define HALO 8
__global__ void k_conv(const float* __restrict__ img, float2* __restrict__ gimg) {
    __shared__ float sIn[TILE+2*HALO][TILE+2*HALO];      // 48x48
    __shared__ float sColG[TILE+2*HALO][TILE];           // 48x32
    __shared__ float sColD[TILE+2*HALO][TILE];
    __shared__ float gtap[17], dtap[17];
    const int b  = blockIdx.z;
    const int x0 = blockIdx.x * TILE;
    const int y0 = blockIdx.y * TILE;
    const int tid = threadIdx.x;
    if (tid == 0) {
        float s = 0.f;
        for (int i = 0; i < 17; ++i) {
            float xv = (float)(i - 8);
            float e  = expf(-0.5f * (xv*0.5f)*(xv*0.5f));
            gtap[i] = e; s += e;
            dtap[i] = -(xv*0.25f) * e;
        }
        for (int i = 0; i < 17; ++i) gtap[i] /= s;
    }
    const float* im = img + b*HW;
    for (int idx = tid; idx < 48*48; idx += blockDim.x) {
        int r = idx / 48, c = idx % 48;
        int gx = x0 + r - HALO, gy = y0 + c - HALO;
        float v = 0.f;
        if (gx >= 0 && gx < Hh && gy >= 0 && gy < Ww) v = im[gx*Ww + gy];
        sIn[r][c] = v;
    }
    __syncthreads();
    for (int idx = tid; idx < 48*TILE; idx += blockDim.x) {
        int r = idx / TILE, c = idx % TILE;
        float ag = 0.f, ad = 0.f;
#pragma unroll
        for (int k = 0; k < 17; ++k) {
            float v = sIn[r][c+k];
            ag += gtap[k]*v;
            ad += dtap[k]*v;
        }
        sColG[r][c] = ag; sColD[r][c] = ad;
    }
    __syncthreads();
    float2* gg = gimg + (size_t)b*HW;
    for (int idx = tid; idx < TILE*TILE; idx += blockDim.x) {
        int xo = idx / TILE, c = idx % TILE;
        float a0 = 0.f, a1 = 0.f;
#pragma unroll
        for (int k = 0; k < 17; ++k) {
            a0 += dtap[k]*sColG[xo+k][c];
            a1 += gtap[k]*sColD[xo+k][c];
        }
        int gx = x0+xo, gy = y0+c;
        gg[gx*Ww+gy] = make_float2(10.f*a0, 10.f*a1);
    }
}

// ---------------- snake: fused Ainv build + 20 implicit-Euler steps --------
__global__ __launch_bounds__(256) void k_snake(const float2* __restrict__ gimg,
                        const float* __restrict__ init, float* __restrict__ pos) {
    __shared__ float sA[NN][NN+1];
    __shared__ float sd[NN], su1[NN], su2[NN], sb1[NN], sL1[NN], sL2[NN], sdinv[NN];
    __shared__ float2 stxy[NN];
    const int b = blockIdx.x;
    const int tid = threadIdx.x;
    const int i = tid >> 2;
    const int q = tid & 3;

    if (tid == 0) {
        for (int k = 0; k < NN; ++k) { sd[k] = 0.f; su1[k] = 0.f; su2[k] = 0.f; }
        for (int k = 0; k < NN-1; ++k) { sd[k] += 0.01f; sd[k+1] += 0.01f; su1[k] -= 0.01f; }
        for (int k = 0; k < NN-2; ++k) {
            sd[k] += 0.01f; sd[k+1] += 0.04f; sd[k+2] += 0.01f;
            su1[k] -= 0.02f; su1[k+1] -= 0.02f; su2[k] += 0.01f;
        }
        for (int k = 0; k < NN; ++k) {
            sd[k]  = 1.0f + 0.1f*sd[k];
            su1[k] = 0.1f*su1[k];
            su2[k] = 0.1f*su2[k];
            sb1[k] = su1[k];
        }
        for (int k = 0; k < NN; ++k) {
            float di = sd[k];
            if (k+1 < NN) {
                float l = sb1[k]/di; sL1[k] = l;
                sd[k+1] -= l*su1[k];
                if (k+2 < NN) su1[k+1] -= l*su2[k];
            }
            if (k+2 < NN) {
                float l = su2[k]/di; sL2[k] = l;
                sb1[k+1] -= l*su1[k];
                sd[k+2]  -= l*su2[k];
            }
        }
    }
    __syncthreads();
    if (tid < NN) sdinv[tid] = 1.0f/sd[tid];
    __syncthreads();
    if (tid < NN) {
        const int t = tid;
        float y[NN], x[NN];
#pragma unroll
        for (int k = 0; k < NN; ++k) {
            float v = (k == t) ? 1.0f : 0.0f;
            if (k >= 1) v -= sL1[k-1]*y[k-1];
            if (k >= 2) v -= sL2[k-2]*y[k-2];
            y[k] = v;
        }
#pragma unroll
        for (int kk = 0; kk < NN; ++kk) {
            int k = NN-1-kk;
            float v = y[k];
            if (k+1 < NN) v -= su1[k]*x[k+1];
            if (k+2 < NN) v -= su2[k]*x[k+2];
            x[k] = v*sdinv[k];
        }
        for (int k = 0; k < NN; ++k) sA[k][t] = x[k];   // column t (symmetric)
    }
    __syncthreads();

    float ar[16];
#pragma unroll
    for (int k = 0; k < 16; ++k) ar[k] = sA[i][q*16 + k];

    float px = init[(b*NN + i)*2 + 0];
    float py = init[(b*NN + i)*2 + 1];
    const float2* g = gimg + (size_t)b*HW;

    for (int s = 0; s < 20; ++s) {
        float x = fminf(fmaxf(px, 0.f), (float)(Hh-1));
        float y = fminf(fmaxf(py, 0.f), (float)(Ww-1));
        int x0i = (int)floorf(x); x0i = min(max(x0i, 0), Hh-2);
        int y0i = (int)floorf(y); y0i = min(max(y0i, 0), Ww-2);
        float fx = x - (float)x0i, fy = y - (float)y0i;
        int base = x0i*Ww + y0i;
        float2 v00 = g[base],    v01 = g[base+1];
        float2 v10 = g[base+Ww], v11 = g[base+Ww+1];
        float t0x = v00.x*(1.f-fy) + v01.x*fy;
        float t0y = v00.y*(1.f-fy) + v01.y*fy;
        float b0x = v10.x*(1.f-fy) + v11.x*fy;
        float b0y = v10.y*(1.f-fy) + v11.y*fy;
        float f0 = t0x*(1.f-fx) + b0x*fx;
        float f1 = t0y*(1.f-fx) + b0y*fx;
        if (q == 0) stxy[i] = make_float2(px + 0.1f*f0, py + 0.1f*f1);
        __syncthreads();
        float ax = 0.f, ay = 0.f;
#pragma unroll
        for (int k = 0; k < 16; ++k) {
            float2 tv = stxy[q*16 + k];
            ax = fmaf(ar[k], tv.x, ax);
            ay = fmaf(ar[k], tv.y, ay);
        }
        ax += __shfl_xor(ax, 1); ay += __shfl_xor(ay, 1);
        ax += __shfl_xor(ax, 2); ay += __shfl_xor(ay, 2);
        px = ax; py = ay;
        __syncthreads();
    }
    if (q == 0) {
        pos[(b*NN+i)*2+0] = px;
        pos[(b*NN+i)*2+1] = py;
    }
}

// ---------------- radial widths: 1 wave per (b,node), early exit -----------
__global__ void k_widths(const float* __restrict__ pred, const float* __restrict__ pos,
                         float* __restrict__ widths) {
    const int blk = blockIdx.x;
    const int b = blk / NN, node = blk % NN;
    const int lane = threadIdx.x;
    const float sx = rintf(pos[(b*NN+node)*2+0]);
    const float sy = rintf(pos[(b*NN+node)*2+1]);
    const float* p = pred + (size_t)b*HW;
    const bool active = lane < 36;
    const float theta = (float)(10*lane) * 0.017453292519943295f;
    const float c = cosf(theta), s = sinf(theta);
    float w = 0.f;
    for (int r = 1; r < Hh; ++r) {
        float rf = (float)r;
        bool hit = false, oob = false;
        if (active) {
            int xi = (int)floorf(sx + rf*c);
            int yi = (int)floorf(sy + rf*s);
            bool inb = (xi >= 0) & (xi < Hh) & (yi >= 0) & (yi < Ww);
            if (!inb) oob = true;
            else if (p[xi*Ww + yi] > 0.f) hit = true;  // sigmoid(-p)<0.5 <=> p>0
        }
        unsigned long long mh = __ballot(hit);
        unsigned long long mo = __ballot(oob);
        if (mh | mo) { w = mh ? (rf - 1.f) : 0.f; break; }
    }
    if (lane == 0) widths[b*NN + node] = w;
}

// ---------------- per-segment invariants: (p0x,p0y,vx,vy) , (1/vv,w0,dw,-) -
__global__ void k_prep(const float* __restrict__ pos, const float* __restrict__ widths,
                       float4* __restrict__ pA, float4* __restrict__ pB) {
    const int tid = threadIdx.x;
    if (tid >= Bb*(NN-1)) return;
    const int b = tid / (NN-1), s = tid % (NN-1);
    float p0x = pos[(b*NN+s)*2+0],   p0y = pos[(b*NN+s)*2+1];
    float p1x = pos[(b*NN+s+1)*2+0], p1y = pos[(b*NN+s+1)*2+1];
    float vx = p1x - p0x, vy = p1y - p0y;
    float vv = vx*vx + vy*vy + 1e-8f;
    float w0 = widths[b*NN+s], w1 = widths[b*NN+s+1];
    pA[b*(NN-1)+s] = make_float4(p0x, p0y, vx, vy);
    pB[b*(NN-1)+s] = make_float4(1.0f/vv, w0, w1 - w0, 0.f);
}

// ---------------- render: squared-distance min + fused loss ----------------
__global__ __launch_bounds__(256) void k_render(const float* __restrict__ pred,
                        const float4* __restrict__ pAg, const float4* __restrict__ pBg,
                        float* __restrict__ partial) {
    __shared__ float red[256];
    const int b = blockIdx.y;
    const int tid = threadIdx.x;
    const int pix = blockIdx.x*256 + tid;
    const float fx = (float)(pix / Ww), fy = (float)(pix % Ww);
    const float4* pA = pAg + b*(NN-1);
    const float4* pB = pBg + b*(NN-1);
    float m1 = 1e30f, m2 = 1e30f;   // min d2, min (d2 - wt^2); d2 includes +1e-12
    for (int s2 = 0; s2 < NN-1; ++s2) {
        const float4 A = pA[s2];     // p0x p0y vx vy   (wave-uniform -> scalar loads)
        const float4 Bv = pB[s2];    // invvv w0 dw -
        float dx = fx - A.x, dy = fy - A.y;
        float t = fmaf(dy, A.w, dx*A.z) * Bv.x;
        t = fminf(fmaxf(t, 0.f), 1.f);
        float ex = fmaf(-t, A.z, dx);
        float ey = fmaf(-t, A.w, dy);
        float d2 = fmaf(ex, ex, fmaf(ey, ey, 1e-12f));
        float wt = fmaf(t, Bv.z, Bv.y);
        m1 = fminf(m1, d2);
        m2 = fminf(m2, fmaf(-wt, wt, d2));
    }
    float dmap = fminf(sqrtf(m1), 15.f);
    float pm = (m2 <= 0.f) ? 1.f : 0.f;
    float pv = pred[(size_t)b*HW + pix];
    float sg = 1.f/(1.f + expf(-pv));
    float t1 = pv - dmap, t2 = sg - pm;
    float acc = t1*t1 + t2*t2;
    red[tid] = acc; __syncthreads();
    for (int off = 128; off > 0; off >>= 1) {
        if (tid < off) red[tid] += red[tid+off];
        __syncthreads();
    }
    if (tid == 0) partial[b*gridDim.x + blockIdx.x] = red[0];
}

__global__ void k_final(const float* __restrict__ partial, float* __restrict__ out, int n) {
    __shared__ double red[256];
    const int tid = threadIdx.x;
    double a = 0.0;
    for (int i = tid; i < n; i += 256) a += (double)partial[i];
    red[tid] = a; __syncthreads();
    for (int off = 128; off > 0; off >>= 1) {
        if (tid < off) red[tid] += red[tid+off];
        __syncthreads();
    }
    if (tid == 0) out[0] = (float)(red[0] / (double)((size_t)Bb*HW));
}

extern "C" void kernel_launch(void* const* d_in, const int* in_sizes, int n_in,
                              void* d_out, int out_size, void* d_ws, size_t ws_size,
                              hipStream_t stream) {
    const float* pred = (const float*)d_in[0];   // [4,1,384,384] f32
    const float* init = (const float*)d_in[1];   // [4,64,2] f32
    float* out = (float*)d_out;
    char* ws = (char*)d_ws;
    // ws layout: params 8064B @0 | pos @16384 | widths @18432 | partial @19456 | gimg @28672
    float4* pA     = (float4*)(ws);                       // 4*63 float4
    float4* pB     = (float4*)(ws + 4096);                // 4*63 float4
    float* pos     = (float*)(ws + 16384);
    float* widths  = (float*)(ws + 18432);
    float* partial = (float*)(ws + 19456);
    float2* gimg   = (float2*)(ws + 28672);

    k_conv  <<<dim3(12,12,4),  dim3(256), 0, stream>>>(pred, gimg);
    k_snake <<<dim3(4),        dim3(256), 0, stream>>>(gimg, init, pos);
    k_widths<<<dim3(Bb*NN),    dim3(64),  0, stream>>>(pred, pos, widths);
    k_prep  <<<dim3(1),        dim3(256), 0, stream>>>(pos, widths, pA, pB);
    k_render<<<dim3(576,Bb),   dim3(256), 0, stream>>>(pred, pA, pB, partial);
    k_final <<<dim3(1),        dim3(256), 0, stream>>>(partial, out, Bb*576);
}